// Round 2
// baseline (75348.364 us; speedup 1.0000x reference)
//
#include <hip/hip_runtime.h>
#include <math.h>

// Persistent-kernel DDE solver.
// D=256, H=1024, N_TAU=10. N derived from out_size.
// 32 WGs x 256 threads; all weights register-resident; one global spin
// barrier per Euler step; per-WG LDS ring buffer for the delayed state.

#define NTAU 10
#define DD   256
#define HH   1024
#define NWG  32
#define TPB  256
#define HPW  (HH / NWG)   // 32 h-rows per WG
#define KPT  64           // z elements per thread (layer 1)

__global__ __launch_bounds__(TPB, 1)
void ndde_persist(const float* __restrict__ x0,
                  const float* __restrict__ W1,
                  const float* __restrict__ b1,
                  const float* __restrict__ W2,
                  const float* __restrict__ b2,
                  const int*   __restrict__ taup,
                  float* __restrict__ out,   // [DD][N+1] row-major
                  float*        P,           // [2][NWG][DD] partial slots (in d_ws)
                  unsigned int* ctr,         // barrier counter (in d_ws, zeroed)
                  int N)
{
    const int w  = blockIdx.x;     // 0..31
    const int t  = threadIdx.x;    // 0..255
    const int r  = t >> 3;         // row-in-WG 0..31
    const int i  = t & 7;          // k-chunk 0..7 (i<4 -> x part, i>=4 -> y part)
    const int row  = w * HPW + r;  // global h row this (r-group) computes
    const int col0 = w * HPW;      // W2 column base for layer 2

    const float dt = 0.1f * (float)(*taup);

    __shared__ __align__(16) float xcur[DD];
    __shared__ __align__(16) float hist[NTAU][DD];  // ring: slot s%10 holds x_{s-10}
    __shared__ __align__(16) float hsh[HPW];

    // ---- prologue: weights -> registers ----
    // Layer-1 chunk: W1[row][i*64 + 4*((j+i)&15) + c]  (j-rotation by i spreads
    // the 8 per-wave LDS broadcast addresses across 8 distinct bank-quads;
    // without it all 8 chunk bases are 64-float multiples -> same banks).
    float4 w1r[16];
    {
        const float* wrow = W1 + (size_t)row * (2 * DD);
        #pragma unroll
        for (int j = 0; j < 16; ++j) {
            int jj = (j + i) & 15;
            w1r[j] = *(const float4*)(wrow + i * KPT + 4 * jj);
        }
    }
    // Layer-2 chunk: W2[t][col0 .. col0+32)
    float4 w2r[8];
    #pragma unroll
    for (int c = 0; c < 8; ++c)
        w2r[c] = *(const float4*)(W2 + (size_t)t * HH + col0 + 4 * c);

    const float b1r = b1[row];
    const float b2r = b2[t];
    const float x0r = x0[t];
    const bool  writer = (r == w);          // WG w owns output rows [8w, 8w+8)
    float* orow = out + (size_t)t * (N + 1);  // running pointer, this thread's row

    xcur[t] = x0r;
    #pragma unroll
    for (int q = 0; q < NTAU; ++q) hist[q][t] = x0r;
    if (writer) orow[0] = x0r;
    __syncthreads();

    int hidx = 0;  // s % NTAU
    for (int s = 0; s < N; ++s) {
        // ---- layer 1: acc = sum_k W1[row][chunk] * z[chunk] ----
        const float* zbase = (i < 4) ? (xcur + (i & 3) * KPT)
                                     : (hist[hidx] + (i & 3) * KPT);
        float ax = 0.f, ay = 0.f, az = 0.f, aw = 0.f;  // 4 indep FMA chains
        #pragma unroll
        for (int j = 0; j < 16; ++j) {
            int jj = (j + i) & 15;
            float4 zv = *(const float4*)(zbase + 4 * jj);
            float4 wv = w1r[j];
            ax = fmaf(wv.x, zv.x, ax);
            ay = fmaf(wv.y, zv.y, ay);
            az = fmaf(wv.z, zv.z, az);
            aw = fmaf(wv.w, zv.w, aw);
        }
        float acc = (ax + ay) + (az + aw);
        // reduce the 8 k-chunk lanes (contiguous within wave)
        acc += __shfl_xor(acc, 1);
        acc += __shfl_xor(acc, 2);
        acc += __shfl_xor(acc, 4);
        if (i == 0) hsh[r] = tanhf(acc + b1r);
        __syncthreads();

        // ---- layer 2: partial_d = sum_c W2[d][col0+c] * h[col0+c] ----
        float px = 0.f, py = 0.f, pz = 0.f, pw = 0.f;
        #pragma unroll
        for (int c = 0; c < 8; ++c) {
            float4 hv = *(const float4*)(&hsh[4 * c]);  // same-addr broadcast
            float4 wv = w2r[c];
            px = fmaf(wv.x, hv.x, px);
            py = fmaf(wv.y, hv.y, py);
            pz = fmaf(wv.z, hv.z, pz);
            pw = fmaf(wv.w, hv.w, pw);
        }
        float p = (px + py) + (pz + pw);

        // ---- publish partial (agent-visible: XCD L2s are not coherent) ----
        float* slot = P + ((size_t)(s & 1) * NWG + w) * DD;
        __hip_atomic_store(slot + t, p, __ATOMIC_RELAXED, __HIP_MEMORY_SCOPE_AGENT);
        __threadfence();   // drain stores to the coherence point
        __syncthreads();   // all 256 threads' partials are now visible

        // ---- global barrier: monotonic counter, leader poll ----
        if (t == 0) {
            __hip_atomic_fetch_add(ctr, 1u, __ATOMIC_RELEASE, __HIP_MEMORY_SCOPE_AGENT);
            const unsigned int target = (unsigned int)(s + 1) * NWG;
            while (__hip_atomic_load(ctr, __ATOMIC_RELAXED, __HIP_MEMORY_SCOPE_AGENT) < target)
                __builtin_amdgcn_s_sleep(1);
        }
        __syncthreads();
        __threadfence();   // acquire side: invalidate before gathering

        // ---- gather all 32 partials for own component t (deterministic order) ----
        float* gp = P + (size_t)(s & 1) * NWG * DD + t;
        float delta = 0.f;
        #pragma unroll
        for (int ww = 0; ww < NWG; ++ww)
            delta += __hip_atomic_load(gp + (size_t)ww * DD, __ATOMIC_RELAXED,
                                       __HIP_MEMORY_SCOPE_AGENT);

        const float xold = xcur[t];
        const float xnew = fmaf(dt, delta + b2r, xold);
        // hist[hidx] (= y_s) fully consumed before the pre-barrier __syncthreads;
        // safe to overwrite with x_s now. Same for xcur.
        hist[hidx][t] = xold;
        xcur[t]       = xnew;
        if (writer) orow[s + 1] = xnew;
        hidx = (hidx + 1 == NTAU) ? 0 : hidx + 1;
        __syncthreads();
    }
}

extern "C" void kernel_launch(void* const* d_in, const int* in_sizes, int n_in,
                              void* d_out, int out_size, void* d_ws, size_t ws_size,
                              hipStream_t stream)
{
    const float* x0  = (const float*)d_in[0];
    const float* W1  = (const float*)d_in[1];
    const float* b1  = (const float*)d_in[2];
    const float* W2  = (const float*)d_in[3];
    const float* b2  = (const float*)d_in[4];
    const int*  taup = (const int*)d_in[5];

    const int Dv = in_sizes[0];           // 256
    const int N  = out_size / Dv - 1;     // 10000

    unsigned int* ctr = (unsigned int*)d_ws;           // 4B used, 256B reserved
    float* P = (float*)((char*)d_ws + 256);            // 2*32*256 floats = 64KB

    // d_ws is poisoned 0xAA before every launch: the barrier counter must start 0.
    hipMemsetAsync(d_ws, 0, 256, stream);

    hipLaunchKernelGGL(ndde_persist, dim3(NWG), dim3(TPB), 0, stream,
                       x0, W1, b1, W2, b2, taup,
                       (float*)d_out, P, ctr, N);
}

// Round 4
// 28497.565 us; speedup vs baseline: 2.6440x; 2.6440x over previous
//
#include <hip/hip_runtime.h>
#include <math.h>

// Persistent-kernel DDE solver.
// D=256, H=1024, N_TAU=10. N derived from out_size.
// 32 WGs x 256 threads; all weights register-resident; one global spin
// barrier per Euler step; per-WG LDS ring buffer for the delayed state.
//
// R2 change (fence removal): all cross-WG traffic (partials P, counter ctr)
// uses relaxed AGENT-scope atomics, which compile to sc1-flagged per-op
// loads/stores that are coherent at the cross-XCD coherence point by
// themselves. The previous __threadfence() calls compiled to whole-L2
// buffer_wbl2/buffer_inv twice per step -> 410MB WRITE / 1.3GB FETCH of
// forced HBM traffic (rocprof R2). Ordering "partial stores done before
// counter add" is provided by __syncthreads() (drains vmcnt before
// s_barrier). RELEASE on the fetch_add would re-emit wbl2 -> RELAXED.

#define NTAU 10
#define DD   256
#define HH   1024
#define NWG  32
#define TPB  256
#define HPW  (HH / NWG)   // 32 h-rows per WG
#define KPT  64           // z elements per thread (layer 1)

__global__ __launch_bounds__(TPB, 1)
void ndde_persist(const float* __restrict__ x0,
                  const float* __restrict__ W1,
                  const float* __restrict__ b1,
                  const float* __restrict__ W2,
                  const float* __restrict__ b2,
                  const int*   __restrict__ taup,
                  float* __restrict__ out,   // [DD][N+1] row-major
                  float*        P,           // [2][NWG][DD] partial slots (in d_ws)
                  unsigned int* ctr,         // barrier counter (in d_ws, zeroed)
                  int N)
{
    const int w  = blockIdx.x;     // 0..31
    const int t  = threadIdx.x;    // 0..255
    const int r  = t >> 3;         // row-in-WG 0..31
    const int i  = t & 7;          // k-chunk 0..7 (i<4 -> x part, i>=4 -> y part)
    const int row  = w * HPW + r;  // global h row this (r-group) computes
    const int col0 = w * HPW;      // W2 column base for layer 2

    const float dt = 0.1f * (float)(*taup);

    __shared__ __align__(16) float xcur[DD];
    __shared__ __align__(16) float hist[NTAU][DD];  // ring: slot s%10 holds x_{s-10}
    __shared__ __align__(16) float hsh[HPW];

    // ---- prologue: weights -> registers ----
    // Layer-1 chunk: W1[row][i*64 + 4*((j+i)&15) + c]  (j-rotation by i spreads
    // the 8 per-wave LDS broadcast addresses across 8 distinct bank-quads).
    float4 w1r[16];
    {
        const float* wrow = W1 + (size_t)row * (2 * DD);
        #pragma unroll
        for (int j = 0; j < 16; ++j) {
            int jj = (j + i) & 15;
            w1r[j] = *(const float4*)(wrow + i * KPT + 4 * jj);
        }
    }
    // Layer-2 chunk: W2[t][col0 .. col0+32)
    float4 w2r[8];
    #pragma unroll
    for (int c = 0; c < 8; ++c)
        w2r[c] = *(const float4*)(W2 + (size_t)t * HH + col0 + 4 * c);

    const float b1r = b1[row];
    const float b2r = b2[t];
    const float x0r = x0[t];
    const bool  writer = (r == w);            // WG w owns output rows [8w, 8w+8)
    float* orow = out + (size_t)t * (N + 1);  // this thread's output row

    xcur[t] = x0r;
    #pragma unroll
    for (int q = 0; q < NTAU; ++q) hist[q][t] = x0r;
    if (writer) orow[0] = x0r;
    __syncthreads();

    int hidx = 0;  // s % NTAU
    for (int s = 0; s < N; ++s) {
        // ---- layer 1: acc = sum_k W1[row][chunk] * z[chunk] ----
        const float* zbase = (i < 4) ? (xcur + (i & 3) * KPT)
                                     : (hist[hidx] + (i & 3) * KPT);
        float ax = 0.f, ay = 0.f, az = 0.f, aw = 0.f;  // 4 indep FMA chains
        #pragma unroll
        for (int j = 0; j < 16; ++j) {
            int jj = (j + i) & 15;
            float4 zv = *(const float4*)(zbase + 4 * jj);
            float4 wv = w1r[j];
            ax = fmaf(wv.x, zv.x, ax);
            ay = fmaf(wv.y, zv.y, ay);
            az = fmaf(wv.z, zv.z, az);
            aw = fmaf(wv.w, zv.w, aw);
        }
        float acc = (ax + ay) + (az + aw);
        // reduce the 8 k-chunk lanes (contiguous within wave)
        acc += __shfl_xor(acc, 1);
        acc += __shfl_xor(acc, 2);
        acc += __shfl_xor(acc, 4);
        if (i == 0) hsh[r] = tanhf(acc + b1r);
        __syncthreads();

        // ---- layer 2: partial_d = sum_c W2[d][col0+c] * h[col0+c] ----
        float px = 0.f, py = 0.f, pz = 0.f, pw = 0.f;
        #pragma unroll
        for (int c = 0; c < 8; ++c) {
            float4 hv = *(const float4*)(&hsh[4 * c]);  // same-addr broadcast
            float4 wv = w2r[c];
            px = fmaf(wv.x, hv.x, px);
            py = fmaf(wv.y, hv.y, py);
            pz = fmaf(wv.z, hv.z, pz);
            pw = fmaf(wv.w, hv.w, pw);
        }
        float p = (px + py) + (pz + pw);

        // ---- publish partial: relaxed agent atomic store = sc1 write-through,
        // coherent at the cross-XCD coherence point on its own (no fence).
        float* slot = P + ((size_t)(s & 1) * NWG + w) * DD;
        __hip_atomic_store(slot + t, p, __ATOMIC_RELAXED, __HIP_MEMORY_SCOPE_AGENT);
        // __syncthreads drains each thread's vmcnt before s_barrier: all 256
        // partial stores are complete (hence visible) before the leader's add.
        __syncthreads();

        // ---- global barrier: monotonic counter, leader poll ----
        if (t == 0) {
            __hip_atomic_fetch_add(ctr, 1u, __ATOMIC_RELAXED, __HIP_MEMORY_SCOPE_AGENT);
            const unsigned int target = (unsigned int)(s + 1) * NWG;
            while (__hip_atomic_load(ctr, __ATOMIC_RELAXED, __HIP_MEMORY_SCOPE_AGENT) < target)
                __builtin_amdgcn_s_sleep(1);
        }
        __syncthreads();

        // ---- gather all 32 partials for own component t (deterministic order).
        // Relaxed agent atomic loads read at the coherence point (no buffer_inv
        // needed; there are no non-atomic cross-WG accesses to cover).
        float* gp = P + (size_t)(s & 1) * NWG * DD + t;
        float delta = 0.f;
        #pragma unroll
        for (int ww = 0; ww < NWG; ++ww)
            delta += __hip_atomic_load(gp + (size_t)ww * DD, __ATOMIC_RELAXED,
                                       __HIP_MEMORY_SCOPE_AGENT);

        const float xold = xcur[t];
        const float xnew = fmaf(dt, delta + b2r, xold);
        // hist[hidx] (= y_s) fully consumed before the pre-barrier __syncthreads;
        // safe to overwrite with x_s now. Same for xcur.
        hist[hidx][t] = xold;
        xcur[t]       = xnew;
        if (writer) orow[s + 1] = xnew;
        hidx = (hidx + 1 == NTAU) ? 0 : hidx + 1;
        __syncthreads();
    }
}

extern "C" void kernel_launch(void* const* d_in, const int* in_sizes, int n_in,
                              void* d_out, int out_size, void* d_ws, size_t ws_size,
                              hipStream_t stream)
{
    const float* x0  = (const float*)d_in[0];
    const float* W1  = (const float*)d_in[1];
    const float* b1  = (const float*)d_in[2];
    const float* W2  = (const float*)d_in[3];
    const float* b2  = (const float*)d_in[4];
    const int*  taup = (const int*)d_in[5];

    const int Dv = in_sizes[0];           // 256
    const int N  = out_size / Dv - 1;     // 10000

    unsigned int* ctr = (unsigned int*)d_ws;           // 4B used, 256B reserved
    float* P = (float*)((char*)d_ws + 256);            // 2*32*256 floats = 64KB

    // d_ws is poisoned 0xAA before every launch: the barrier counter must start 0.
    hipMemsetAsync(d_ws, 0, 256, stream);

    hipLaunchKernelGGL(ndde_persist, dim3(NWG), dim3(TPB), 0, stream,
                       x0, W1, b1, W2, b2, taup,
                       (float*)d_out, P, ctr, N);
}